// Round 8
// baseline (268.996 us; speedup 1.0000x reference)
//
#include <hip/hip_runtime.h>

#define NE 8
#define CAP 1024
#define HD 1024
#define ID 1408
#define TT 2048

typedef __attribute__((ext_vector_type(8))) short bf16x8;
typedef __attribute__((ext_vector_type(4))) float f32x4;
typedef unsigned short u16;
typedef unsigned int u32;
typedef unsigned long long u64;

__device__ __forceinline__ u16 f2bf(float f) {
  u32 u = __float_as_uint(f);
  u = (u + 0x7fffu + ((u >> 16) & 1u)) >> 16;
  return (u16)u;
}

__device__ __forceinline__ bf16x8 pack8(float4 a, float4 b) {
  bf16x8 r;
  r[0] = (short)f2bf(a.x); r[1] = (short)f2bf(a.y);
  r[2] = (short)f2bf(a.z); r[3] = (short)f2bf(a.w);
  r[4] = (short)f2bf(b.x); r[5] = (short)f2bf(b.y);
  r[6] = (short)f2bf(b.z); r[7] = (short)f2bf(b.w);
  return r;
}

__device__ __forceinline__ void async_cp16(const void* g, void* l) {
  __builtin_amdgcn_global_load_lds(
      (const __attribute__((address_space(1))) u32*)g,
      (__attribute__((address_space(3))) u32*)l, 16, 0, 0);
}

// ---------------- prep: route (block 0) + w1 il-cvt + x cvt + out zero -------
#define W1ROWS (NE * 2 * ID)       // 22528 blocks, one per (row,expert)
#define XBLK (TT * HD / 4 / 256)   // 2048 blocks
#define OZB (TT * HD / 4 / 256)    // 2048 blocks
__global__ __launch_bounds__(256) void prep_kernel(
    const float4* __restrict__ w1, ushort4* __restrict__ bw1,
    const float4* __restrict__ x, ushort4* __restrict__ bx,
    const int* __restrict__ ids, int* __restrict__ rowmap,
    int* __restrict__ counts, float4* __restrict__ outz) {
  int b = blockIdx.x;
  int tid = threadIdx.x;
  if (b == 0) {
    __shared__ unsigned char ids_s[TT * 2];
    __shared__ int sc[256][NE + 1];
    for (int i = tid; i < TT * 2; i += 256) ids_s[i] = (unsigned char)ids[i];
    __syncthreads();
    int base = tid * 16;
    u64 own64 = 0;
#pragma unroll
    for (int j = 0; j < 16; ++j) own64 += 1ull << (ids_s[base + j] * 8);
    int own[NE];
#pragma unroll
    for (int e = 0; e < NE; ++e) {
      own[e] = (int)((own64 >> (e * 8)) & 0xff);
      sc[tid][e] = own[e];
    }
    __syncthreads();
    for (int off = 1; off < 256; off <<= 1) {
      int v[NE];
      if (tid >= off) {
#pragma unroll
        for (int e = 0; e < NE; ++e) v[e] = sc[tid - off][e];
      }
      __syncthreads();
      if (tid >= off) {
#pragma unroll
        for (int e = 0; e < NE; ++e) sc[tid][e] += v[e];
      }
      __syncthreads();
    }
    if (tid == 255) {
#pragma unroll
      for (int e = 0; e < NE; ++e) counts[e] = sc[255][e] < CAP ? sc[255][e] : CAP;
    }
    int excl[NE];
#pragma unroll
    for (int e = 0; e < NE; ++e) excl[e] = sc[tid][e] - own[e];
    __syncthreads();
#pragma unroll
    for (int e = 0; e < NE; ++e) sc[tid][e] = excl[e];
#pragma unroll
    for (int j = 0; j < 16; ++j) {
      int f = base + j;
      int e = ids_s[f];
      int p = sc[tid][e]++;
      if (p < CAP) rowmap[e * CAP + p] = f;
    }
    return;
  }
  int bb = b - 1;
  if (bb < W1ROWS) {
    int n = bb % (2 * ID);
    int e = bb / (2 * ID);
    int j = (n < ID) ? n : (n - ID);
    int np = (j >> 4) * 32 + (j & 15) + ((n < ID) ? 0 : 16);
    float4 v = w1[((size_t)e * 2 * ID + n) * (HD / 4) + tid];
    ushort4 o;
    o.x = f2bf(v.x); o.y = f2bf(v.y); o.z = f2bf(v.z); o.w = f2bf(v.w);
    bw1[((size_t)e * 2 * ID + np) * (HD / 4) + tid] = o;
  } else if (bb < W1ROWS + XBLK) {
    size_t i = (size_t)(bb - W1ROWS) * 256 + tid;
    float4 v = x[i];
    ushort4 o;
    o.x = f2bf(v.x); o.y = f2bf(v.y); o.z = f2bf(v.z); o.w = f2bf(v.w);
    bx[i] = o;
  } else {
    size_t i = (size_t)(bb - W1ROWS - XBLK) * 256 + tid;
    float4 z = {0.f, 0.f, 0.f, 0.f};
    outz[i] = z;
  }
}

// ---------------- GEMM1 (+ interleaved riders): 64x128, BK=32, depth-2 -------
// 3 x 12KB buffers (A 4K @0, B 8K @4K) = 36KB -> 4 blocks/CU (was 2). LDS uses
// paired-row layout: two 64B K-rows share one 128B LDS row, XOR-8 swizzled:
// store slot s of row-pair rp holds row 2*rp+((s^(rp&7))>>2), chunk (s^..)&3
// (inverse applied in the per-thread GLOBAL address; LDS dest stays linear for
// global_load_lds). Read: off=(r>>1)*128+((((r&1)<<2)+q)^((r>>1)&7))*16 ->
// verified 2-way-max bank aliasing per 16-lane phase (free, m136).
// vmcnt: 3 loads/step, steady wait vmcnt(3) (stage t+1 stays in flight).
#define G1BUF 12288
__global__ __launch_bounds__(256, 4) void gemm1_kernel(
    const u16* __restrict__ A, const u16* __restrict__ B, u16* __restrict__ Hb,
    const int* __restrict__ rowmap, const int* __restrict__ counts,
    const float4* __restrict__ W2, bf16x8* __restrict__ bw2) {
  int bid = blockIdx.x;
  int tid = threadIdx.x;
  int grp = bid >> 3, sub = bid & 7;
  int q7 = grp / 7, r7 = grp - q7 * 7;
  if (r7 == 2 || r7 == 5) {  // ---- w2 cvt rider: 88 groups x 8 = 704 ----
    int r = (q7 * 2 + (r7 == 5 ? 1 : 0)) * 8 + sub;
#pragma unroll
    for (int k2 = 0; k2 < 4; ++k2) {
      size_t base4 = ((size_t)r * 4 + k2) * 1024;
      float4 v0 = W2[base4 + tid * 2];
      float4 v1 = W2[base4 + tid * 2 + 1];
      float4 v2 = W2[base4 + 512 + tid * 2];
      float4 v3 = W2[base4 + 512 + tid * 2 + 1];
      bf16x8* dst = bw2 + base4 / 2;
      dst[tid] = pack8(v0, v1);
      dst[256 + tid] = pack8(v2, v3);
    }
    return;
  }
  int tg = q7 * 5 + r7 - (r7 > 2 ? 1 : 0) - (r7 > 5 ? 1 : 0);  // 0..219
  int e = sub;
  int my = tg % 10;
  int n0 = (tg / 10) * 128;
  int count = counts[e];
  int lane = tid & 63, wid = tid >> 6;
  int wm = wid >> 1, wn = wid & 1;
  int q = lane >> 4, lm = lane & 15;

  __shared__ __align__(16) char sm[3 * G1BUF];

  // staging source mapping (inverse of the paired-row XOR-8 store)
  int rp8 = tid >> 3;
  int h = (tid & 7) ^ (rp8 & 7);
  int r0 = 2 * rp8 + (h >> 2);   // tile row this thread stages (0..63)
  int c0 = (h & 3) * 8;          // elem offset within the 32-elem K-slice
  const u16* bP[2];
#pragma unroll
  for (int i = 0; i < 2; ++i)
    bP[i] = B + ((size_t)e * 2 * ID + n0 + r0 + 64 * i) * HD + c0;

  // K-invariant ds_read byte offsets
  int offA[2], offB[4];
#pragma unroll
  for (int mi = 0; mi < 2; ++mi) {
    int r = wm * 32 + mi * 16 + lm;
    offA[mi] = (r >> 1) * 128 + (((((r & 1) << 2) + q) ^ ((r >> 1) & 7)) << 4);
  }
#pragma unroll
  for (int ni = 0; ni < 4; ++ni) {
    int r = wn * 64 + ni * 16 + lm;
    offB[ni] = 4096 + (r >> 1) * 128 + (((((r & 1) << 2) + q) ^ ((r >> 1) & 7)) << 4);
  }

#define STAGE1(base, kt)                                         \
  do {                                                           \
    int ko_ = (kt) * 32;                                         \
    char* sb_ = (base);                                          \
    async_cp16(aP + ko_, sb_ + tid * 16);                        \
    async_cp16(bP[0] + ko_, sb_ + 4096 + tid * 16);              \
    async_cp16(bP[1] + ko_, sb_ + 8192 + tid * 16);              \
  } while (0)

  for (int m0 = my * 64; m0 < count; m0 += 640) {
    int gr = m0 + r0;
    int f = (gr < count) ? rowmap[e * CAP + gr] : 0;
    const u16* aP = A + (size_t)(f >> 1) * HD + c0;

    f32x4 zero = {0.f, 0.f, 0.f, 0.f};
    f32x4 acc[2][4];
#pragma unroll
    for (int mi = 0; mi < 2; ++mi)
#pragma unroll
      for (int ni = 0; ni < 4; ++ni) acc[mi][ni] = zero;

    STAGE1(sm, 0);
    STAGE1(sm + G1BUF, 1);
    int p = 0, pn2 = 2;
    for (int kt = 0; kt < HD / 32; ++kt) {
      if (kt == HD / 32 - 1)
        asm volatile("s_waitcnt vmcnt(0)\ns_barrier" ::: "memory");
      else
        asm volatile("s_waitcnt vmcnt(3)\ns_barrier" ::: "memory");
      const char* sb = sm + p * G1BUF;
      if (kt + 2 < HD / 32) STAGE1(sm + pn2 * G1BUF, kt + 2);
      bf16x8 af[2], bfr[4];
#pragma unroll
      for (int mi = 0; mi < 2; ++mi)
        af[mi] = *(const bf16x8*)(sb + offA[mi]);
#pragma unroll
      for (int ni = 0; ni < 4; ++ni)
        bfr[ni] = *(const bf16x8*)(sb + offB[ni]);
      __builtin_amdgcn_s_setprio(1);
#pragma unroll
      for (int mi = 0; mi < 2; ++mi)
#pragma unroll
        for (int ni = 0; ni < 4; ++ni)
          acc[mi][ni] = __builtin_amdgcn_mfma_f32_16x16x32_bf16(af[mi], bfr[ni], acc[mi][ni], 0, 0, 0);
      __builtin_amdgcn_s_setprio(0);
      p = (p == 2) ? 0 : p + 1;
      pn2 = (pn2 == 2) ? 0 : pn2 + 1;
    }
    __syncthreads();  // full drain before LDS reuse by epilogue

    // ---- fused SiLU epilogue: merged 64x64 u16 tile (unchanged) ----
    u16* smOut = (u16*)sm;  // [64][72] u16
#pragma unroll
    for (int mi = 0; mi < 2; ++mi) {
#pragma unroll
      for (int k = 0; k < 2; ++k) {
        int colL = wn * 32 + k * 16 + lm;
#pragma unroll
        for (int r = 0; r < 4; ++r) {
          float g2 = acc[mi][2 * k][r];
          float u = acc[mi][2 * k + 1][r];
          float a = g2 / (1.f + __expf(-g2)) * u;
          int row = wm * 32 + mi * 16 + q * 4 + r;
          smOut[row * 72 + colL] = f2bf(a);
        }
      }
    }
    __syncthreads();
    {
      int row = tid >> 2, seg = tid & 3;
      const u16* sp = smOut + row * 72 + seg * 16;
      bf16x8 v0 = *(const bf16x8*)sp;
      bf16x8 v1 = *(const bf16x8*)(sp + 8);
      u16* dp = Hb + ((size_t)e * CAP + m0 + row) * ID + (n0 >> 1) + seg * 16;
      *(bf16x8*)dp = v0;
      *(bf16x8*)(dp + 8) = v1;
    }
    __syncthreads();  // smOut aliases staging buffers; fence before next m0
  }
}

// ---------------- GEMM2: 64x64, BK=32, depth-2, 24KB -> 6 blocks/CU ----------
#define G2BUF 8192
__global__ __launch_bounds__(256, 4) void gemm2_kernel(
    const u16* __restrict__ A, const u16* __restrict__ B, float* __restrict__ out,
    const int* __restrict__ rowmap, const int* __restrict__ counts,
    const float* __restrict__ tw) {
  int idx = blockIdx.x;
  int e = idx & 7;
  int tg = idx >> 3;
  int my = tg % 10;
  int n0 = (tg / 10) * 64;
  int count = counts[e];
  int tid = threadIdx.x;
  int lane = tid & 63, wid = tid >> 6;
  int wm = wid >> 1, wn = wid & 1;
  int q = lane >> 4, lm = lane & 15;

  __shared__ __align__(16) char sm[3 * G2BUF];  // per buf: A 4KB @0, B 4KB @4K

  int rp8 = tid >> 3;
  int h = (tid & 7) ^ (rp8 & 7);
  int r0 = 2 * rp8 + (h >> 2);
  int c0 = (h & 3) * 8;
  const u16* bP = B + ((size_t)e * HD + n0 + r0) * ID + c0;

  int offA[2], offB[2];
#pragma unroll
  for (int mi = 0; mi < 2; ++mi) {
    int r = wm * 32 + mi * 16 + lm;
    offA[mi] = (r >> 1) * 128 + (((((r & 1) << 2) + q) ^ ((r >> 1) & 7)) << 4);
  }
#pragma unroll
  for (int ni = 0; ni < 2; ++ni) {
    int r = wn * 32 + ni * 16 + lm;
    offB[ni] = 4096 + (r >> 1) * 128 + (((((r & 1) << 2) + q) ^ ((r >> 1) & 7)) << 4);
  }

#define STAGE2(base, kt)                                         \
  do {                                                           \
    int ko_ = (kt) * 32;                                         \
    char* sb_ = (base);                                          \
    async_cp16(aP + ko_, sb_ + tid * 16);                        \
    async_cp16(bP + ko_, sb_ + 4096 + tid * 16);                 \
  } while (0)

  for (int m0 = my * 64; m0 < count; m0 += 640) {
    const u16* aP = A + ((size_t)e * CAP + m0 + r0) * ID + c0;

    f32x4 zero = {0.f, 0.f, 0.f, 0.f};
    f32x4 acc[2][2];
#pragma unroll
    for (int mi = 0; mi < 2; ++mi)
#pragma unroll
      for (int ni = 0; ni < 2; ++ni) acc[mi][ni] = zero;

    STAGE2(sm, 0);
    STAGE2(sm + G2BUF, 1);
    int p = 0, pn2 = 2;
    for (int kt = 0; kt < ID / 32; ++kt) {
      if (kt == ID / 32 - 1)
        asm volatile("s_waitcnt vmcnt(0)\ns_barrier" ::: "memory");
      else
        asm volatile("s_waitcnt vmcnt(2)\ns_barrier" ::: "memory");
      const char* sb = sm + p * G2BUF;
      if (kt + 2 < ID / 32) STAGE2(sm + pn2 * G2BUF, kt + 2);
      bf16x8 af[2], bfr[2];
#pragma unroll
      for (int mi = 0; mi < 2; ++mi)
        af[mi] = *(const bf16x8*)(sb + offA[mi]);
#pragma unroll
      for (int ni = 0; ni < 2; ++ni)
        bfr[ni] = *(const bf16x8*)(sb + offB[ni]);
      __builtin_amdgcn_s_setprio(1);
#pragma unroll
      for (int mi = 0; mi < 2; ++mi)
#pragma unroll
        for (int ni = 0; ni < 2; ++ni)
          acc[mi][ni] = __builtin_amdgcn_mfma_f32_16x16x32_bf16(af[mi], bfr[ni], acc[mi][ni], 0, 0, 0);
      __builtin_amdgcn_s_setprio(0);
      p = (p == 2) ? 0 : p + 1;
      pn2 = (pn2 == 2) ? 0 : pn2 + 1;
    }

    // fused combine epilogue: out[token, col] += w * y
#pragma unroll
    for (int mi = 0; mi < 2; ++mi) {
#pragma unroll
      for (int r = 0; r < 4; ++r) {
        int grow = m0 + wm * 32 + mi * 16 + q * 4 + r;
        if (grow < count) {
          int f = rowmap[e * CAP + grow];
          float w = tw[f];
          int t = f >> 1;
#pragma unroll
          for (int ni = 0; ni < 2; ++ni) {
            int col = n0 + wn * 32 + ni * 16 + lm;
            atomicAdd(&out[(size_t)t * HD + col], w * acc[mi][ni][r]);
          }
        }
      }
    }
    __syncthreads();  // sm safe before next m0 iteration's STAGE2
  }
}

extern "C" void kernel_launch(void* const* d_in, const int* in_sizes, int n_in,
                              void* d_out, int out_size, void* d_ws, size_t ws_size,
                              hipStream_t stream) {
  const float* hidden = (const float*)d_in[0];
  const float* w1 = (const float*)d_in[1];
  const float* w2 = (const float*)d_in[2];
  const float* tw = (const float*)d_in[3];
  const int* ids = (const int*)d_in[4];
  float* out = (float*)d_out;

  char* p = (char*)d_ws;
  auto alloc = [&](size_t b) { char* r = p; p += (b + 255) & ~(size_t)255; return r; };
  u16* bw1 = (u16*)alloc((size_t)NE * 2 * ID * HD * 2);   // 46.1 MB (interleaved)
  u16* bw2 = (u16*)alloc((size_t)NE * HD * ID * 2);        // 23.1 MB
  u16* bx = (u16*)alloc((size_t)TT * HD * 2);              // 4.2 MB
  u16* hbuf = (u16*)alloc((size_t)NE * CAP * ID * 2);      // 23.1 MB
  int* rowmap = (int*)alloc((size_t)NE * CAP * 4);
  int* counts = (int*)alloc((size_t)NE * 4);

  // prep: route (block 0) + w1 il-cvt + x cvt + out zero
  prep_kernel<<<1 + W1ROWS + XBLK + OZB, 256, 0, stream>>>(
      (const float4*)w1, (ushort4*)bw1, (const float4*)hidden, (ushort4*)bx,
      ids, rowmap, counts, (float4*)out);

  // GEMM1 + SiLU, w2-cvt riders interleaved 2-of-7 groups: 308 groups x 8
  gemm1_kernel<<<308 * 8, 256, 0, stream>>>(
      bx, bw1, hbuf, rowmap, counts, (const float4*)w2, (bf16x8*)bw2);

  // GEMM2 + combine: 8 experts x 10 m-groups x 16 n-tiles
  gemm2_kernel<<<8 * 10 * 16, 256, 0, stream>>>(
      hbuf, bw2, out, rowmap, counts, tw);
}

// Round 9
// 258.079 us; speedup vs baseline: 1.0423x; 1.0423x over previous
//
#include <hip/hip_runtime.h>

#define NE 8
#define CAP 1024
#define HD 1024
#define ID 1408
#define TT 2048

typedef __attribute__((ext_vector_type(8))) short bf16x8;
typedef __attribute__((ext_vector_type(4))) float f32x4;
typedef unsigned short u16;
typedef unsigned int u32;
typedef unsigned long long u64;

__device__ __forceinline__ u16 f2bf(float f) {
  u32 u = __float_as_uint(f);
  u = (u + 0x7fffu + ((u >> 16) & 1u)) >> 16;
  return (u16)u;
}

__device__ __forceinline__ bf16x8 pack8(float4 a, float4 b) {
  bf16x8 r;
  r[0] = (short)f2bf(a.x); r[1] = (short)f2bf(a.y);
  r[2] = (short)f2bf(a.z); r[3] = (short)f2bf(a.w);
  r[4] = (short)f2bf(b.x); r[5] = (short)f2bf(b.y);
  r[6] = (short)f2bf(b.z); r[7] = (short)f2bf(b.w);
  return r;
}

__device__ __forceinline__ void async_cp16(const void* g, void* l) {
  __builtin_amdgcn_global_load_lds(
      (const __attribute__((address_space(1))) u32*)g,
      (__attribute__((address_space(3))) u32*)l, 16, 0, 0);
}

// ---------------- prep: route (block 0) + w1 il-cvt + x cvt ------------------
// r0-proven small-block streaming form. out-zero moved to gemm1 riders.
#define W1ROWS (NE * 2 * ID)       // 22528 blocks, one per (row,expert)
#define XBLK (TT * HD / 4 / 256)   // 2048 blocks
__global__ __launch_bounds__(256) void prep_kernel(
    const float4* __restrict__ w1, ushort4* __restrict__ bw1,
    const float4* __restrict__ x, ushort4* __restrict__ bx,
    const int* __restrict__ ids, int* __restrict__ rowmap,
    int* __restrict__ counts) {
  int b = blockIdx.x;
  int tid = threadIdx.x;
  if (b == 0) {
    __shared__ unsigned char ids_s[TT * 2];
    __shared__ int sc[256][NE + 1];
    for (int i = tid; i < TT * 2; i += 256) ids_s[i] = (unsigned char)ids[i];
    __syncthreads();
    int base = tid * 16;
    u64 own64 = 0;
#pragma unroll
    for (int j = 0; j < 16; ++j) own64 += 1ull << (ids_s[base + j] * 8);
    int own[NE];
#pragma unroll
    for (int e = 0; e < NE; ++e) {
      own[e] = (int)((own64 >> (e * 8)) & 0xff);
      sc[tid][e] = own[e];
    }
    __syncthreads();
    for (int off = 1; off < 256; off <<= 1) {
      int v[NE];
      if (tid >= off) {
#pragma unroll
        for (int e = 0; e < NE; ++e) v[e] = sc[tid - off][e];
      }
      __syncthreads();
      if (tid >= off) {
#pragma unroll
        for (int e = 0; e < NE; ++e) sc[tid][e] += v[e];
      }
      __syncthreads();
    }
    if (tid == 255) {
#pragma unroll
      for (int e = 0; e < NE; ++e) counts[e] = sc[255][e] < CAP ? sc[255][e] : CAP;
    }
    int excl[NE];
#pragma unroll
    for (int e = 0; e < NE; ++e) excl[e] = sc[tid][e] - own[e];
    __syncthreads();
#pragma unroll
    for (int e = 0; e < NE; ++e) sc[tid][e] = excl[e];
#pragma unroll
    for (int j = 0; j < 16; ++j) {
      int f = base + j;
      int e = ids_s[f];
      int p = sc[tid][e]++;
      if (p < CAP) rowmap[e * CAP + p] = f;
    }
    return;
  }
  int bb = b - 1;
  if (bb < W1ROWS) {
    // w1 interleave-cvt: gate j -> (j>>4)*32+(j&15), up -> +16
    int n = bb % (2 * ID);
    int e = bb / (2 * ID);
    int j = (n < ID) ? n : (n - ID);
    int np = (j >> 4) * 32 + (j & 15) + ((n < ID) ? 0 : 16);
    float4 v = w1[((size_t)e * 2 * ID + n) * (HD / 4) + tid];
    ushort4 o;
    o.x = f2bf(v.x); o.y = f2bf(v.y); o.z = f2bf(v.z); o.w = f2bf(v.w);
    bw1[((size_t)e * 2 * ID + np) * (HD / 4) + tid] = o;
  } else {
    size_t i = (size_t)(bb - W1ROWS) * 256 + tid;
    float4 v = x[i];
    ushort4 o;
    o.x = f2bf(v.x); o.y = f2bf(v.y); o.z = f2bf(v.z); o.w = f2bf(v.w);
    bx[i] = o;
  }
}

// ---------------- GEMM1 (+ interleaved riders): 64x128, BK=64, depth-2 -------
// r7-verbatim pipeline: 3 x 24KB LDS rotation, stage(t+2) in step t,
// s_waitcnt vmcnt(6)+s_barrier fused, never drained to 0 in the main loop.
// Riders interleaved 3-of-10 groups: w2 cvt (88 rider-groups) + out-zero
// (8 rider-groups). Grid = 320 groups x 8 blocks; e = bid&7 keeps the
// expert->XCD L2 affinity (FETCH ~50MB, r7-verified).
#define G1BUF 24576
__global__ __launch_bounds__(256) void gemm1_kernel(
    const u16* __restrict__ A, const u16* __restrict__ B, u16* __restrict__ Hb,
    const int* __restrict__ rowmap, const int* __restrict__ counts,
    const float4* __restrict__ W2, bf16x8* __restrict__ bw2,
    float4* __restrict__ outz) {
  int bid = blockIdx.x;
  int tid = threadIdx.x;
  int grp = bid >> 3, sub = bid & 7;
  int sup = grp / 10, r10 = grp - sup * 10;
  if (r10 == 2 || r10 == 5 || r10 == 8) {  // ---- rider groups (3 of 10) ----
    int which = (r10 == 2) ? 0 : (r10 == 5) ? 1 : 2;
    int r = sup * 3 + which;  // 0..95
    if (r < 88) {             // w2 cvt rider: 88 groups x 8 blocks x 4 chunks
      int rb = r * 8 + sub;
#pragma unroll
      for (int k2 = 0; k2 < 4; ++k2) {
        size_t base4 = ((size_t)rb * 4 + k2) * 1024;
        float4 v0 = W2[base4 + tid * 2];
        float4 v1 = W2[base4 + tid * 2 + 1];
        float4 v2 = W2[base4 + 512 + tid * 2];
        float4 v3 = W2[base4 + 512 + tid * 2 + 1];
        bf16x8* dst = bw2 + base4 / 2;
        dst[tid] = pack8(v0, v1);
        dst[256 + tid] = pack8(v2, v3);
      }
    } else {  // out-zero rider: 8 groups x 8 blocks x 8192 float4
      size_t base = (size_t)((r - 88) * 8 + sub) * 8192;
      float4 z = {0.f, 0.f, 0.f, 0.f};
#pragma unroll
      for (int i2 = 0; i2 < 32; ++i2) outz[base + i2 * 256 + tid] = z;
    }
    return;
  }
  int tg = sup * 7 + r10 - (r10 > 2 ? 1 : 0) - (r10 > 5 ? 1 : 0) - (r10 > 8 ? 1 : 0);
  if (tg >= 220) return;  // 4 spare groups
  int e = sub;
  int my = tg % 10;
  int n0 = (tg / 10) * 128;
  int count = counts[e];
  int lane = tid & 63, wid = tid >> 6;
  int wm = wid >> 1, wn = wid & 1;
  int q = lane >> 4, lm = lane & 15;

  __shared__ __align__(16) char sm[3 * G1BUF];  // per buf: A 8KB @0, B 16KB @8K

  int rloc = tid >> 3;
  int chs = ((tid & 7) ^ (rloc & 7)) * 8;
  const u16* bP[4];
#pragma unroll
  for (int i = 0; i < 4; ++i)
    bP[i] = B + ((size_t)e * 2 * ID + n0 + rloc + 32 * i) * HD + chs;

#define STAGE1(base, kt)                                             \
  do {                                                               \
    int ko_ = (kt) * 64;                                             \
    char* sb_ = (base);                                              \
    async_cp16(aP[0] + ko_, sb_ + (0 * 256 + tid) * 16);             \
    async_cp16(aP[1] + ko_, sb_ + (1 * 256 + tid) * 16);             \
    async_cp16(bP[0] + ko_, sb_ + 8192 + (0 * 256 + tid) * 16);      \
    async_cp16(bP[1] + ko_, sb_ + 8192 + (1 * 256 + tid) * 16);      \
    async_cp16(bP[2] + ko_, sb_ + 8192 + (2 * 256 + tid) * 16);      \
    async_cp16(bP[3] + ko_, sb_ + 8192 + (3 * 256 + tid) * 16);      \
  } while (0)

  for (int m0 = my * 64; m0 < count; m0 += 640) {
    const u16* aP[2];
#pragma unroll
    for (int i = 0; i < 2; ++i) {
      int gr = m0 + rloc + 32 * i;
      int f = (gr < count) ? rowmap[e * CAP + gr] : 0;
      aP[i] = A + (size_t)(f >> 1) * HD + chs;
    }

    f32x4 zero = {0.f, 0.f, 0.f, 0.f};
    f32x4 acc[2][4];
#pragma unroll
    for (int mi = 0; mi < 2; ++mi)
#pragma unroll
      for (int ni = 0; ni < 4; ++ni) acc[mi][ni] = zero;

    STAGE1(sm, 0);
    STAGE1(sm + G1BUF, 1);
    int p = 0, pn2 = 2;
    for (int kt = 0; kt < HD / 64; ++kt) {
      if (kt == HD / 64 - 1)
        asm volatile("s_waitcnt vmcnt(0)\ns_barrier" ::: "memory");
      else
        asm volatile("s_waitcnt vmcnt(6)\ns_barrier" ::: "memory");
      const char* sb = sm + p * G1BUF;
      if (kt + 2 < HD / 64) STAGE1(sm + pn2 * G1BUF, kt + 2);
#pragma unroll
      for (int s = 0; s < 2; ++s) {
        int cs = ((s * 4 + q) ^ (lm & 7)) * 16;
        bf16x8 af[2], bfr[4];
#pragma unroll
        for (int mi = 0; mi < 2; ++mi)
          af[mi] = *(const bf16x8*)(sb + (wm * 32 + mi * 16 + lm) * 128 + cs);
#pragma unroll
        for (int ni = 0; ni < 4; ++ni)
          bfr[ni] = *(const bf16x8*)(sb + 8192 + (wn * 64 + ni * 16 + lm) * 128 + cs);
        __builtin_amdgcn_s_setprio(1);
#pragma unroll
        for (int mi = 0; mi < 2; ++mi)
#pragma unroll
          for (int ni = 0; ni < 4; ++ni)
            acc[mi][ni] = __builtin_amdgcn_mfma_f32_16x16x32_bf16(af[mi], bfr[ni], acc[mi][ni], 0, 0, 0);
        __builtin_amdgcn_s_setprio(0);
      }
      p = (p == 2) ? 0 : p + 1;
      pn2 = (pn2 == 2) ? 0 : pn2 + 1;
    }
    __syncthreads();  // full drain before LDS reuse by epilogue

    // ---- fused SiLU epilogue: merged 64x64 u16 tile ----
    u16* smOut = (u16*)sm;  // [64][72] u16
#pragma unroll
    for (int mi = 0; mi < 2; ++mi) {
#pragma unroll
      for (int k = 0; k < 2; ++k) {
        int colL = wn * 32 + k * 16 + lm;
#pragma unroll
        for (int r = 0; r < 4; ++r) {
          float g2 = acc[mi][2 * k][r];
          float u = acc[mi][2 * k + 1][r];
          float a = g2 / (1.f + __expf(-g2)) * u;
          int row = wm * 32 + mi * 16 + q * 4 + r;
          smOut[row * 72 + colL] = f2bf(a);
        }
      }
    }
    __syncthreads();
    {
      int row = tid >> 2, seg = tid & 3;
      const u16* sp = smOut + row * 72 + seg * 16;
      bf16x8 v0 = *(const bf16x8*)sp;
      bf16x8 v1 = *(const bf16x8*)(sp + 8);
      u16* dp = Hb + ((size_t)e * CAP + m0 + row) * ID + (n0 >> 1) + seg * 16;
      *(bf16x8*)dp = v0;
      *(bf16x8*)(dp + 8) = v1;
    }
    __syncthreads();  // smOut aliases staging buffers; fence before next m0
  }
}

// ---------------- GEMM2: 64x128 (mirrors gemm1 geometry), BK=64, depth-2 -----
// Widened from 64x64: per s-step 6 ds_reads feed 16 MFMA (was 4:4) and the
// B panel gains 2x n-reuse. Grid 640 = 8 n-tiles x 10 my x 8 e (e fastest).
#define G2BUF 24576
__global__ __launch_bounds__(256) void gemm2_kernel(
    const u16* __restrict__ A, const u16* __restrict__ B, float* __restrict__ out,
    const int* __restrict__ rowmap, const int* __restrict__ counts,
    const float* __restrict__ tw) {
  int idx = blockIdx.x;
  int e = idx & 7;
  int tg = idx >> 3;
  int my = tg % 10;
  int n0 = (tg / 10) * 128;
  int count = counts[e];
  int tid = threadIdx.x;
  int lane = tid & 63, wid = tid >> 6;
  int wm = wid >> 1, wn = wid & 1;
  int q = lane >> 4, lm = lane & 15;

  __shared__ __align__(16) char sm[3 * G2BUF];  // per buf: A 8KB @0, B 16KB @8K

  int rloc = tid >> 3;
  int chs = ((tid & 7) ^ (rloc & 7)) * 8;
  const u16* bP[4];
#pragma unroll
  for (int i = 0; i < 4; ++i)
    bP[i] = B + ((size_t)e * HD + n0 + rloc + 32 * i) * ID + chs;

#define STAGE2(base, kt)                                             \
  do {                                                               \
    int ko_ = (kt) * 64;                                             \
    char* sb_ = (base);                                              \
    async_cp16(aP[0] + ko_, sb_ + (0 * 256 + tid) * 16);             \
    async_cp16(aP[1] + ko_, sb_ + (1 * 256 + tid) * 16);             \
    async_cp16(bP[0] + ko_, sb_ + 8192 + (0 * 256 + tid) * 16);      \
    async_cp16(bP[1] + ko_, sb_ + 8192 + (1 * 256 + tid) * 16);      \
    async_cp16(bP[2] + ko_, sb_ + 8192 + (2 * 256 + tid) * 16);      \
    async_cp16(bP[3] + ko_, sb_ + 8192 + (3 * 256 + tid) * 16);      \
  } while (0)

  for (int m0 = my * 64; m0 < count; m0 += 640) {
    const u16* aP[2];
#pragma unroll
    for (int i = 0; i < 2; ++i)
      aP[i] = A + ((size_t)e * CAP + m0 + rloc + 32 * i) * ID + chs;

    f32x4 zero = {0.f, 0.f, 0.f, 0.f};
    f32x4 acc[2][4];
#pragma unroll
    for (int mi = 0; mi < 2; ++mi)
#pragma unroll
      for (int ni = 0; ni < 4; ++ni) acc[mi][ni] = zero;

    STAGE2(sm, 0);
    STAGE2(sm + G2BUF, 1);
    int p = 0, pn2 = 2;
    for (int kt = 0; kt < ID / 64; ++kt) {
      if (kt == ID / 64 - 1)
        asm volatile("s_waitcnt vmcnt(0)\ns_barrier" ::: "memory");
      else
        asm volatile("s_waitcnt vmcnt(6)\ns_barrier" ::: "memory");
      const char* sb = sm + p * G2BUF;
      if (kt + 2 < ID / 64) STAGE2(sm + pn2 * G2BUF, kt + 2);
#pragma unroll
      for (int s = 0; s < 2; ++s) {
        int cs = ((s * 4 + q) ^ (lm & 7)) * 16;
        bf16x8 af[2], bfr[4];
#pragma unroll
        for (int mi = 0; mi < 2; ++mi)
          af[mi] = *(const bf16x8*)(sb + (wm * 32 + mi * 16 + lm) * 128 + cs);
#pragma unroll
        for (int ni = 0; ni < 4; ++ni)
          bfr[ni] = *(const bf16x8*)(sb + 8192 + (wn * 64 + ni * 16 + lm) * 128 + cs);
        __builtin_amdgcn_s_setprio(1);
#pragma unroll
        for (int mi = 0; mi < 2; ++mi)
#pragma unroll
          for (int ni = 0; ni < 4; ++ni)
            acc[mi][ni] = __builtin_amdgcn_mfma_f32_16x16x32_bf16(af[mi], bfr[ni], acc[mi][ni], 0, 0, 0);
        __builtin_amdgcn_s_setprio(0);
      }
      p = (p == 2) ? 0 : p + 1;
      pn2 = (pn2 == 2) ? 0 : pn2 + 1;
    }

    // fused combine epilogue: out[token, col] += w * y
#pragma unroll
    for (int mi = 0; mi < 2; ++mi) {
#pragma unroll
      for (int r = 0; r < 4; ++r) {
        int grow = m0 + wm * 32 + mi * 16 + q * 4 + r;
        if (grow < count) {
          int f = rowmap[e * CAP + grow];
          float w = tw[f];
          int t = f >> 1;
#pragma unroll
          for (int ni = 0; ni < 4; ++ni) {
            int col = n0 + wn * 64 + ni * 16 + lm;
            atomicAdd(&out[(size_t)t * HD + col], w * acc[mi][ni][r]);
          }
        }
      }
    }
    __syncthreads();  // sm safe before next m0 iteration's STAGE2
  }
}

extern "C" void kernel_launch(void* const* d_in, const int* in_sizes, int n_in,
                              void* d_out, int out_size, void* d_ws, size_t ws_size,
                              hipStream_t stream) {
  const float* hidden = (const float*)d_in[0];
  const float* w1 = (const float*)d_in[1];
  const float* w2 = (const float*)d_in[2];
  const float* tw = (const float*)d_in[3];
  const int* ids = (const int*)d_in[4];
  float* out = (float*)d_out;

  char* p = (char*)d_ws;
  auto alloc = [&](size_t b) { char* r = p; p += (b + 255) & ~(size_t)255; return r; };
  u16* bw1 = (u16*)alloc((size_t)NE * 2 * ID * HD * 2);   // 46.1 MB (interleaved)
  u16* bw2 = (u16*)alloc((size_t)NE * HD * ID * 2);        // 23.1 MB
  u16* bx = (u16*)alloc((size_t)TT * HD * 2);              // 4.2 MB
  u16* hbuf = (u16*)alloc((size_t)NE * CAP * ID * 2);      // 23.1 MB
  int* rowmap = (int*)alloc((size_t)NE * CAP * 4);
  int* counts = (int*)alloc((size_t)NE * 4);

  // prep: route (block 0) + w1 il-cvt + x cvt
  prep_kernel<<<1 + W1ROWS + XBLK, 256, 0, stream>>>(
      (const float4*)w1, (ushort4*)bw1, (const float4*)hidden, (ushort4*)bx,
      ids, rowmap, counts);

  // GEMM1 + SiLU, riders (w2-cvt + out-zero) interleaved 3-of-10 groups
  gemm1_kernel<<<320 * 8, 256, 0, stream>>>(
      bx, bw1, hbuf, rowmap, counts, (const float4*)w2, (bf16x8*)bw2,
      (float4*)out);

  // GEMM2 + combine: 64x128 tiles, 8 n-tiles x 10 my x 8 experts
  gemm2_kernel<<<8 * 10 * 8, 256, 0, stream>>>(
      hbuf, bw2, out, rowmap, counts, tw);
}